// Round 5
// baseline (313.164 us; speedup 1.0000x reference)
//
#include <hip/hip_runtime.h>

typedef unsigned short u16;
typedef short s16x8 __attribute__((ext_vector_type(8)));
typedef float f32x4 __attribute__((ext_vector_type(4)));

__device__ __forceinline__ u16 f2bf(float f) {
  union { float f; unsigned u; } x; x.f = f;
  unsigned r = (x.u + 0x7fffu + ((x.u >> 16) & 1u)) >> 16;
  return (u16)r;
}
__device__ __forceinline__ u16 f2bf_t(float f) {   // truncating (for P in [0,1])
  union { float f; unsigned u; } x; x.f = f;
  return (u16)(x.u >> 16);
}
__device__ __forceinline__ float bf2f(u16 u) {
  union { unsigned u; float f; } x; x.u = ((unsigned)u) << 16;
  return x.f;
}

__device__ __forceinline__ void load_lds16(const u16* g, void* lds) {
  __builtin_amdgcn_global_load_lds(
      (const __attribute__((address_space(1))) unsigned int*)g,
      (__attribute__((address_space(3))) unsigned int*)lds, 16, 0, 0);
}

// ---------------- prep kernels ----------------

__global__ __launch_bounds__(256) void cast_bf16_kernel(const float* __restrict__ src,
                                                        u16* __restrict__ dst, int n4) {
  int id = blockIdx.x * 256 + threadIdx.x;
  if (id >= n4) return;
  float4 v = ((const float4*)src)[id];
  u16* d = dst + (size_t)id * 4;
  d[0] = f2bf(v.x); d[1] = f2bf(v.y); d[2] = f2bf(v.z); d[3] = f2bf(v.w);
}

__global__ __launch_bounds__(256) void pack_qkv_w_kernel(const float* __restrict__ wq,
                                                         const float* __restrict__ wk,
                                                         const float* __restrict__ wv,
                                                         u16* __restrict__ dst) {
  int id = blockIdx.x * 256 + threadIdx.x;   // over 3072*512 float4 groups
  if (id >= 3072 * 512) return;
  int row = id >> 9;
  int c4 = (id & 511) * 4;
  const float* src; int srow;
  if (row < 2048)      { src = wq; srow = row; }
  else if (row < 2560) { src = wk; srow = row - 2048; }
  else                 { src = wv; srow = row - 2560; }
  float4 v = *(const float4*)&src[(size_t)srow * 2048 + c4];
  u16* d = dst + (size_t)row * 2048 + c4;
  d[0] = f2bf(v.x); d[1] = f2bf(v.y); d[2] = f2bf(v.z); d[3] = f2bf(v.w);
}

__global__ __launch_bounds__(256) void pack_bias_kernel(const float* __restrict__ bq,
                                                        const float* __restrict__ bk,
                                                        const float* __restrict__ bv,
                                                        float* __restrict__ dst) {
  int id = blockIdx.x * 256 + threadIdx.x;
  if (id >= 3072) return;
  float v;
  if (id < 2048)      v = bq[id];
  else if (id < 2560) v = bk[id - 2048];
  else                v = bv[id - 2560];
  dst[id] = v;
}

__global__ __launch_bounds__(256) void rope_table_kernel(float* __restrict__ cosb,
                                                         float* __restrict__ sinb) {
  int id = blockIdx.x * 256 + threadIdx.x;   // S*64 = 131072
  if (id >= 2048 * 64) return;
  int s = id >> 6, i = id & 63;
  float freq = powf(10000.0f, -(float)i / 64.0f);
  float ang = (float)s * freq;
  cosb[id] = cosf(ang);
  sinb[id] = sinf(ang);
}

// in-place RoPE on bf16 buffer laid out [rows][128], rows = NH*S
__global__ __launch_bounds__(256) void rope_kernel(u16* __restrict__ p,
                                                   const float* __restrict__ cosb,
                                                   const float* __restrict__ sinb,
                                                   int total) {
  int id = blockIdx.x * 256 + threadIdx.x;   // total = rows*64
  if (id >= total) return;
  int i = id & 63;
  int rs = id >> 6;
  int s = rs & 2047;                          // S = 2048
  size_t base = (size_t)rs * 128;
  float x1 = bf2f(p[base + i]);
  float x2 = bf2f(p[base + i + 64]);
  float c = cosb[s * 64 + i], sn = sinb[s * 64 + i];
  p[base + i]      = f2bf(x1 * c - x2 * sn);
  p[base + i + 64] = f2bf(x2 * c + x1 * sn);
}

// V [8][2048][128] -> Vt [8][128][2048]
__global__ __launch_bounds__(256) void transpose_v_kernel(const u16* __restrict__ V,
                                                          u16* __restrict__ Vt) {
  __shared__ u16 tile[64][130];
  const int t = threadIdx.x;
  const int hb = blockIdx.x, s0 = blockIdx.y * 64;
  const u16* src = V + ((size_t)hb * 2048 + s0) * 128;
#pragma unroll
  for (int i = 0; i < 4; ++i) {
    int c = i * 256 + t;            // 0..1023
    int s = c >> 4, d8 = (c & 15) * 8;
    *(s16x8*)&tile[s][d8] = *(const s16x8*)&src[(size_t)s * 128 + d8];
  }
  __syncthreads();
  u16* dst = Vt + (size_t)hb * 128 * 2048 + s0;
#pragma unroll
  for (int i = 0; i < 4; ++i) {
    int c = i * 256 + t;
    int d = c & 127, s8 = (c >> 7) * 8;
    s16x8 v;
#pragma unroll
    for (int e = 0; e < 8; ++e) v[e] = (short)tile[s8 + e][d];
    *(s16x8*)&dst[(size_t)d * 2048 + s8] = v;
  }
}

// ---------------- bf16 MFMA GEMM, BK=64: C[m,n] = sum_k A[m,k]*B[n,k] (+bias) ------
// mode 0: scatter to Q/K/V bf16 buffers (+bias). mode 1: plain f32 C.
__global__ __launch_bounds__(256) void gemm_bt_kernel(
    const u16* __restrict__ A, const u16* __restrict__ Bw,
    const float* __restrict__ bias,
    float* __restrict__ C, int ldc,
    u16* __restrict__ Qp, u16* __restrict__ Kp, u16* __restrict__ Vp,
    int M, int N, int K, int mode) {
  __shared__ u16 sA[128 * 64];   // 16 KB
  __shared__ u16 sB[128 * 64];   // 16 KB
  const int t = threadIdx.x;
  const int w = t >> 6, l = t & 63;
  const int lg = l >> 4, lr = l & 15;
  const int wm = (w >> 1) * 64, wn = (w & 1) * 64;
  const int m0 = blockIdx.y * 128, n0 = blockIdx.x * 128;

  f32x4 acc[4][4];
#pragma unroll
  for (int i = 0; i < 4; ++i)
#pragma unroll
    for (int j = 0; j < 4; ++j)
#pragma unroll
      for (int r = 0; r < 4; ++r) acc[i][j][r] = 0.0f;

  for (int k0 = 0; k0 < K; k0 += 64) {
    // stage A,B tiles [128][64]: 1024 chunks each, 4/thread, wave-linear dest
#pragma unroll
    for (int i = 0; i < 4; ++i) {
      int c = i * 256 + t;                 // byte dest = c*16 = i*4096 + w*1024 + l*16
      int row = c >> 3, col8 = (c & 7) * 8;
      load_lds16(A + (size_t)(m0 + row) * K + k0 + col8,
                 (char*)sA + i * 4096 + w * 1024);
      load_lds16(Bw + (size_t)(n0 + row) * K + k0 + col8,
                 (char*)sB + i * 4096 + w * 1024);
    }
    __syncthreads();
#pragma unroll
    for (int kc = 0; kc < 2; ++kc) {
      s16x8 af[4], bf[4];
#pragma unroll
      for (int m = 0; m < 4; ++m)
        af[m] = *(const s16x8*)&sA[(wm + m * 16 + lr) * 64 + kc * 32 + lg * 8];
#pragma unroll
      for (int n = 0; n < 4; ++n)
        bf[n] = *(const s16x8*)&sB[(wn + n * 16 + lr) * 64 + kc * 32 + lg * 8];
#pragma unroll
      for (int m = 0; m < 4; ++m)
#pragma unroll
        for (int n = 0; n < 4; ++n)
          acc[m][n] = __builtin_amdgcn_mfma_f32_16x16x32_bf16(af[m], bf[n], acc[m][n], 0, 0, 0);
    }
    __syncthreads();
  }

#pragma unroll
  for (int m = 0; m < 4; ++m) {
#pragma unroll
    for (int n = 0; n < 4; ++n) {
#pragma unroll
      for (int r = 0; r < 4; ++r) {
        int row = m0 + wm + m * 16 + (lg << 2) + r;
        int col = n0 + wn + n * 16 + lr;
        float val = acc[m][n][r];
        if (mode == 0) {
          val += bias[col];
          int b = row >> 11, s = row & 2047;
          u16 bvv = f2bf(val);
          if (col < 2048) {
            int h = col >> 7, d = col & 127;
            Qp[(((size_t)(b * 16 + h)) * 2048 + s) * 128 + d] = bvv;
          } else if (col < 2560) {
            int cc = col - 2048; int kh = cc >> 7, d = cc & 127;
            Kp[(((size_t)(b * 4 + kh)) * 2048 + s) * 128 + d] = bvv;
          } else {
            int cc = col - 2560; int kh = cc >> 7, d = cc & 127;
            Vp[(((size_t)(b * 4 + kh)) * 2048 + s) * 128 + d] = bvv;
          }
        } else {
          C[(size_t)row * ldc + col] = val;
        }
      }
    }
  }
}

// ---------------- MFMA flash attention v5 (causal, GQA, 2-phase prefetch) ----------
// Q: [B*16][S][128] bf16 (rope'd), K: [B*4][S][128] bf16 (rope'd), Vt: [B*4][128][S]
// O (att): [B,S,2048] bf16.  grid = (32, 32), block = 256 (4 waves).
// Block q-tile = 64 rows, heavy-first (qc = 31 - by); wave w owns rows qw=q0+w*16..+15.
// KV tile = 64, DOUBLE-BUFFERED: issue global_load_lds for tile kt+1, compute tile kt,
// one __syncthreads per step (drains vmcnt). 73.5 KB LDS -> 2 blocks/CU.
// K/Vt staged with pre-swizzled global chunk (cc ^= row&7); reads apply same XOR.
// Softmax: exp2-domain, defer-max THR=8, per-lane partial denominator.
// Frag layouts (HW-verified): A/B row(col)=l&15, k=(l>>4)*8+e; C/D col=l&15, row=(l>>4)*4+r.
__global__ __launch_bounds__(256) void flash_mfma_kernel(const u16* __restrict__ Q,
                                                         const u16* __restrict__ Kb,
                                                         const u16* __restrict__ Vtb,
                                                         u16* __restrict__ O) {
  const int S = 2048;
  __shared__ u16 sK[2 * 64 * 128];   // [buf][j][d], 16B-chunk XOR (j&7)
  __shared__ u16 sVt[2 * 128 * 64];  // [buf][d][j], 16B-chunk XOR (d&7)
  __shared__ u16 sP[4 * 16 * 76];    // per-wave P slabs, stride 76

  const int t = threadIdx.x, w = t >> 6, l = t & 63;
  const int lg = l >> 4, lr = l & 15;
  const int bh = blockIdx.x, b = bh >> 4, h = bh & 15, kvh = h >> 2;
  const int qc = 31 - blockIdx.y;            // heavy blocks dispatch first
  const int q0 = qc * 64;
  const int qw = q0 + w * 16;

  const u16* qbase = Q + ((size_t)bh * S + qw) * 128;
  const u16* kbase = Kb + ((size_t)(b * 4 + kvh)) * S * 128;
  const u16* vtbase = Vtb + ((size_t)(b * 4 + kvh)) * 128 * S;

  // Q fragments: qa[kc][e] = Q[qw + lr][kc*32 + lg*8 + e]
  s16x8 qa[4];
#pragma unroll
  for (int kc = 0; kc < 4; ++kc)
    qa[kc] = *(const s16x8*)&qbase[(size_t)lr * 128 + kc * 32 + lg * 8];

  f32x4 o[8];
#pragma unroll
  for (int dt = 0; dt < 8; ++dt)
#pragma unroll
    for (int r = 0; r < 4; ++r) o[dt][r] = 0.0f;
  float mrun[4], lsum[4];   // lsum is a PER-LANE partial (this lane's 4 columns)
#pragma unroll
  for (int r = 0; r < 4; ++r) { mrun[r] = -3e38f; lsum[r] = 0.0f; }

  u16* sPw = &sP[w * 16 * 76];
  const float C2 = 0.12753785f;   // (1/sqrt(128)) * log2(e)
  const int nt = qc + 1;

  // staging helpers: per-wave quarter, source-swizzled, wave-linear LDS dest
  auto stage = [&](int kt, int buf) {
#pragma unroll
    for (int i = 0; i < 4; ++i) {
      int c = w * 256 + i * 64 + l;
      int j = c >> 4, cc = (c & 15) ^ (j & 7);
      load_lds16(kbase + ((size_t)(kt * 64 + j) * 128 + cc * 8),
                 (char*)sK + buf * 16384 + (w * 4096 + i * 1024));
    }
#pragma unroll
    for (int i = 0; i < 4; ++i) {
      int c = w * 256 + i * 64 + l;
      int d = c >> 3, cc = (c & 7) ^ (d & 7);
      load_lds16(vtbase + ((size_t)d * S + kt * 64 + cc * 8),
                 (char*)sVt + buf * 16384 + (w * 4096 + i * 1024));
    }
  };

  stage(0, 0);
  __syncthreads();   // drains vmcnt -> buf0 ready

  int cur = 0;
  for (int kt = 0; kt < nt; ++kt) {
    if (kt + 1 < nt) stage(kt + 1, cur ^ 1);   // prefetch next tile (overlaps compute)

    const u16* sKc = &sK[cur * 8192];
    const u16* sVc = &sVt[cur * 8192];

    // ---- QK^T: 16 MFMA ----
    f32x4 sc[4];
#pragma unroll
    for (int n = 0; n < 4; ++n)
#pragma unroll
      for (int r = 0; r < 4; ++r) sc[n][r] = 0.0f;
#pragma unroll
    for (int n = 0; n < 4; ++n) {
      int j = n * 16 + lr;
#pragma unroll
      for (int kc = 0; kc < 4; ++kc) {
        s16x8 kf = *(const s16x8*)&sKc[j * 128 + (((kc * 4 + lg) ^ (lr & 7)) * 8)];
        sc[n] = __builtin_amdgcn_mfma_f32_16x16x32_bf16(qa[kc], kf, sc[n], 0, 0, 0);
      }
    }

    // ---- online softmax (exp2 domain, defer-max THR=8, per-lane lsum) ----
    const bool needmask = (kt * 64 + 63 > qw);
#pragma unroll
    for (int r = 0; r < 4; ++r) {
      float a0 = sc[0][r], a1 = sc[1][r], a2 = sc[2][r], a3 = sc[3][r];
      if (needmask) {
        int qi = qw + lg * 4 + r;
        int j0 = kt * 64 + lr;
        a0 = (j0 <= qi) ? a0 : -3e38f;
        a1 = (j0 + 16 <= qi) ? a1 : -3e38f;
        a2 = (j0 + 32 <= qi) ? a2 : -3e38f;
        a3 = (j0 + 48 <= qi) ? a3 : -3e38f;
      }
      float mt = fmaxf(fmaxf(a0, a1), fmaxf(a2, a3));
#pragma unroll
      for (int off = 1; off < 16; off <<= 1) mt = fmaxf(mt, __shfl_xor(mt, off));
      float mt2 = mt * C2;
      float M = mrun[r];
      bool resc = (mt2 > M + 8.0f);
      float Mn = resc ? mt2 : M;
      float p0 = exp2f(__builtin_fmaf(a0, C2, -Mn));
      float p1 = exp2f(__builtin_fmaf(a1, C2, -Mn));
      float p2 = exp2f(__builtin_fmaf(a2, C2, -Mn));
      float p3 = exp2f(__builtin_fmaf(a3, C2, -Mn));
      float ps = (p0 + p1) + (p2 + p3);
      if (resc) {
        float corr = exp2f(M - Mn);
        lsum[r] = lsum[r] * corr + ps;
        mrun[r] = Mn;
#pragma unroll
        for (int dt = 0; dt < 8; ++dt) o[dt][r] *= corr;
      } else {
        lsum[r] += ps;
      }
      int prow = (lg * 4 + r) * 76;
      sPw[prow + lr]      = f2bf_t(p0);
      sPw[prow + 16 + lr] = f2bf_t(p1);
      sPw[prow + 32 + lr] = f2bf_t(p2);
      sPw[prow + 48 + lr] = f2bf_t(p3);
    }

    // ---- PV: 16 MFMA (wave-local sP dependency) ----
    s16x8 pa0 = *(const s16x8*)&sPw[lr * 76 + lg * 8];
    s16x8 pa1 = *(const s16x8*)&sPw[lr * 76 + 32 + lg * 8];
#pragma unroll
    for (int dt = 0; dt < 8; ++dt) {
      int vrow = (dt * 16 + lr) * 64;
      s16x8 vt0 = *(const s16x8*)&sVc[vrow + ((lg ^ (lr & 7)) * 8)];
      s16x8 vt1 = *(const s16x8*)&sVc[vrow + (((4 + lg) ^ (lr & 7)) * 8)];
      o[dt] = __builtin_amdgcn_mfma_f32_16x16x32_bf16(pa0, vt0, o[dt], 0, 0, 0);
      o[dt] = __builtin_amdgcn_mfma_f32_16x16x32_bf16(pa1, vt1, o[dt], 0, 0, 0);
    }

    __syncthreads();   // drains vmcnt (next buf staged) + protects cur buf reuse
    cur ^= 1;
  }

  // epilogue: reduce per-lane denominators across the row's 16 lanes, normalize, store
#pragma unroll
  for (int r = 0; r < 4; ++r) {
    float ls = lsum[r];
#pragma unroll
    for (int off = 1; off < 16; off <<= 1) ls += __shfl_xor(ls, off);
    float inv = 1.0f / ls;
    int qi = qw + lg * 4 + r;
    size_t base = ((size_t)b * S + qi) * 2048 + h * 128;
#pragma unroll
    for (int dt = 0; dt < 8; ++dt)
      O[base + dt * 16 + lr] = f2bf(o[dt][r] * inv);
  }
}

// ---------------- launch ----------------

extern "C" void kernel_launch(void* const* d_in, const int* in_sizes, int n_in,
                              void* d_out, int out_size, void* d_ws, size_t ws_size,
                              hipStream_t stream) {
  const float* x  = (const float*)d_in[0];
  const float* wq = (const float*)d_in[1];
  const float* bq = (const float*)d_in[2];
  const float* wk = (const float*)d_in[3];
  const float* bk = (const float*)d_in[4];
  const float* wv = (const float*)d_in[5];
  const float* bv = (const float*)d_in[6];
  const float* wo = (const float*)d_in[7];
  float* out = (float*)d_out;

  char* ws = (char*)d_ws;
  u16* xb    = (u16*)ws;    ws += (size_t)4096 * 2048 * 2;
  u16* wqkv  = (u16*)ws;    ws += (size_t)3072 * 2048 * 2;
  float* bqkv = (float*)ws; ws += (size_t)3072 * 4;
  u16* wob   = (u16*)ws;    ws += (size_t)2048 * 2048 * 2;
  u16* Qb    = (u16*)ws;    ws += (size_t)32 * 2048 * 128 * 2;
  u16* Kbuf  = (u16*)ws;    ws += (size_t)8 * 2048 * 128 * 2;
  u16* Vbuf  = (u16*)ws;    ws += (size_t)8 * 2048 * 128 * 2;
  u16* Vt    = (u16*)ws;    ws += (size_t)8 * 128 * 2048 * 2;
  float* cosb = (float*)ws; ws += (size_t)2048 * 64 * 4;
  float* sinb = (float*)ws; ws += (size_t)2048 * 64 * 4;
  u16* att   = (u16*)ws;    ws += (size_t)4096 * 2048 * 2;

  cast_bf16_kernel<<<8192, 256, 0, stream>>>(x, xb, 4096 * 2048 / 4);
  pack_qkv_w_kernel<<<6144, 256, 0, stream>>>(wq, wk, wv, wqkv);
  pack_bias_kernel<<<12, 256, 0, stream>>>(bq, bk, bv, bqkv);
  cast_bf16_kernel<<<4096, 256, 0, stream>>>(wo, wob, 2048 * 2048 / 4);
  rope_table_kernel<<<512, 256, 0, stream>>>(cosb, sinb);

  gemm_bt_kernel<<<dim3(24, 32), 256, 0, stream>>>(xb, wqkv, bqkv, nullptr, 0,
                                                   Qb, Kbuf, Vbuf, 4096, 3072, 2048, 0);
  transpose_v_kernel<<<dim3(8, 32), 256, 0, stream>>>(Vbuf, Vt);
  rope_kernel<<<16384, 256, 0, stream>>>(Qb, cosb, sinb, 32 * 2048 * 64);
  rope_kernel<<<4096, 256, 0, stream>>>(Kbuf, cosb, sinb, 8 * 2048 * 64);

  flash_mfma_kernel<<<dim3(32, 32), 256, 0, stream>>>(Qb, Kbuf, Vt, att);

  gemm_bt_kernel<<<dim3(16, 32), 256, 0, stream>>>(att, wob, nullptr, out, 2048,
                                                   nullptr, nullptr, nullptr, 4096, 2048, 2048, 1);
}

// Round 6
// 293.871 us; speedup vs baseline: 1.0656x; 1.0656x over previous
//
#include <hip/hip_runtime.h>

typedef unsigned short u16;
typedef short s16x8 __attribute__((ext_vector_type(8)));
typedef float f32x4 __attribute__((ext_vector_type(4)));

__device__ __forceinline__ u16 f2bf(float f) {
  union { float f; unsigned u; } x; x.f = f;
  unsigned r = (x.u + 0x7fffu + ((x.u >> 16) & 1u)) >> 16;
  return (u16)r;
}
__device__ __forceinline__ u16 f2bf_t(float f) {   // truncating (for P in [0,1])
  union { float f; unsigned u; } x; x.f = f;
  return (u16)(x.u >> 16);
}
__device__ __forceinline__ float bf2f(u16 u) {
  union { unsigned u; float f; } x; x.u = ((unsigned)u) << 16;
  return x.f;
}

__device__ __forceinline__ void load_lds16(const u16* g, void* lds) {
  __builtin_amdgcn_global_load_lds(
      (const __attribute__((address_space(1))) unsigned int*)g,
      (__attribute__((address_space(3))) unsigned int*)lds, 16, 0, 0);
}

// ---------------- prep kernels ----------------

__global__ __launch_bounds__(256) void cast_bf16_kernel(const float* __restrict__ src,
                                                        u16* __restrict__ dst, int n4) {
  int id = blockIdx.x * 256 + threadIdx.x;
  if (id >= n4) return;
  float4 v = ((const float4*)src)[id];
  u16* d = dst + (size_t)id * 4;
  d[0] = f2bf(v.x); d[1] = f2bf(v.y); d[2] = f2bf(v.z); d[3] = f2bf(v.w);
}

__global__ __launch_bounds__(256) void pack_qkv_w_kernel(const float* __restrict__ wq,
                                                         const float* __restrict__ wk,
                                                         const float* __restrict__ wv,
                                                         u16* __restrict__ dst) {
  int id = blockIdx.x * 256 + threadIdx.x;   // over 3072*512 float4 groups
  if (id >= 3072 * 512) return;
  int row = id >> 9;
  int c4 = (id & 511) * 4;
  const float* src; int srow;
  if (row < 2048)      { src = wq; srow = row; }
  else if (row < 2560) { src = wk; srow = row - 2048; }
  else                 { src = wv; srow = row - 2560; }
  float4 v = *(const float4*)&src[(size_t)srow * 2048 + c4];
  u16* d = dst + (size_t)row * 2048 + c4;
  d[0] = f2bf(v.x); d[1] = f2bf(v.y); d[2] = f2bf(v.z); d[3] = f2bf(v.w);
}

__global__ __launch_bounds__(256) void pack_bias_kernel(const float* __restrict__ bq,
                                                        const float* __restrict__ bk,
                                                        const float* __restrict__ bv,
                                                        float* __restrict__ dst) {
  int id = blockIdx.x * 256 + threadIdx.x;
  if (id >= 3072) return;
  float v;
  if (id < 2048)      v = bq[id];
  else if (id < 2560) v = bk[id - 2048];
  else                v = bv[id - 2560];
  dst[id] = v;
}

__global__ __launch_bounds__(256) void rope_table_kernel(float* __restrict__ cosb,
                                                         float* __restrict__ sinb) {
  int id = blockIdx.x * 256 + threadIdx.x;   // S*64 = 131072
  if (id >= 2048 * 64) return;
  int s = id >> 6, i = id & 63;
  float freq = powf(10000.0f, -(float)i / 64.0f);
  float ang = (float)s * freq;
  cosb[id] = cosf(ang);
  sinb[id] = sinf(ang);
}

// in-place RoPE on bf16 buffer laid out [rows][128], rows = NH*S
__global__ __launch_bounds__(256) void rope_kernel(u16* __restrict__ p,
                                                   const float* __restrict__ cosb,
                                                   const float* __restrict__ sinb,
                                                   int total) {
  int id = blockIdx.x * 256 + threadIdx.x;   // total = rows*64
  if (id >= total) return;
  int i = id & 63;
  int rs = id >> 6;
  int s = rs & 2047;                          // S = 2048
  size_t base = (size_t)rs * 128;
  float x1 = bf2f(p[base + i]);
  float x2 = bf2f(p[base + i + 64]);
  float c = cosb[s * 64 + i], sn = sinb[s * 64 + i];
  p[base + i]      = f2bf(x1 * c - x2 * sn);
  p[base + i + 64] = f2bf(x2 * c + x1 * sn);
}

// V [8][2048][128] -> Vt [8][128][2048]
__global__ __launch_bounds__(256) void transpose_v_kernel(const u16* __restrict__ V,
                                                          u16* __restrict__ Vt) {
  __shared__ u16 tile[64][130];
  const int t = threadIdx.x;
  const int hb = blockIdx.x, s0 = blockIdx.y * 64;
  const u16* src = V + ((size_t)hb * 2048 + s0) * 128;
#pragma unroll
  for (int i = 0; i < 4; ++i) {
    int c = i * 256 + t;            // 0..1023
    int s = c >> 4, d8 = (c & 15) * 8;
    *(s16x8*)&tile[s][d8] = *(const s16x8*)&src[(size_t)s * 128 + d8];
  }
  __syncthreads();
  u16* dst = Vt + (size_t)hb * 128 * 2048 + s0;
#pragma unroll
  for (int i = 0; i < 4; ++i) {
    int c = i * 256 + t;
    int d = c & 127, s8 = (c >> 7) * 8;
    s16x8 v;
#pragma unroll
    for (int e = 0; e < 8; ++e) v[e] = (short)tile[s8 + e][d];
    *(s16x8*)&dst[(size_t)d * 2048 + s8] = v;
  }
}

// ---------------- bf16 MFMA GEMM, BK=64, T2-swizzled LDS, T1 XCD block swizzle ----
// C[m,n] = sum_k A[m,k]*B[n,k] (+bias)
// mode 0: scatter to Q/K/V bf16 buffers (+bias). mode 1: plain f32 C.
// LDS tiles [128][64] (128B row stride) staged via global_load_lds with
// SOURCE-swizzled chunk (cc = (c&7)^(row&7)); fragment reads apply the same XOR
// -> ds_read_b128 spans all 32 banks, 2 lanes/slot (free). [G4 / rule #21]
__global__ __launch_bounds__(256) void gemm_bt_kernel(
    const u16* __restrict__ A, const u16* __restrict__ Bw,
    const float* __restrict__ bias,
    float* __restrict__ C, int ldc,
    u16* __restrict__ Qp, u16* __restrict__ Kp, u16* __restrict__ Vp,
    int M, int N, int K, int mode) {
  __shared__ u16 sA[128 * 64];   // 16 KB
  __shared__ u16 sB[128 * 64];   // 16 KB
  const int t = threadIdx.x;
  const int w = t >> 6, l = t & 63;
  const int lg = l >> 4, lr = l & 15;
  const int wm = (w >> 1) * 64, wn = (w & 1) * 64;

  // T1: XCD-aware block swizzle (nwg % 8 == 0 for both grids used)
  const int nwg = gridDim.x * gridDim.y;
  const int id = blockIdx.y * gridDim.x + blockIdx.x;
  const int swz = (id & 7) * (nwg >> 3) + (id >> 3);
  const int m0 = (swz / gridDim.x) * 128, n0 = (swz % gridDim.x) * 128;

  f32x4 acc[4][4];
#pragma unroll
  for (int i = 0; i < 4; ++i)
#pragma unroll
    for (int j = 0; j < 4; ++j)
#pragma unroll
      for (int r = 0; r < 4; ++r) acc[i][j][r] = 0.0f;

  for (int k0 = 0; k0 < K; k0 += 64) {
    // stage A,B tiles [128][64]: 1024 16B chunks each, 4/thread, wave-linear dest,
    // source chunk XOR-swizzled by row&7
#pragma unroll
    for (int i = 0; i < 4; ++i) {
      int c = i * 256 + t;                 // dest byte = c*16 = i*4096 + w*1024 + l*16
      int row = c >> 3, cc = (c & 7) ^ (row & 7);
      load_lds16(A + (size_t)(m0 + row) * K + k0 + cc * 8,
                 (char*)sA + i * 4096 + w * 1024);
      load_lds16(Bw + (size_t)(n0 + row) * K + k0 + cc * 8,
                 (char*)sB + i * 4096 + w * 1024);
    }
    __syncthreads();
#pragma unroll
    for (int kc = 0; kc < 2; ++kc) {
      s16x8 af[4], bf[4];
#pragma unroll
      for (int m = 0; m < 4; ++m)
        af[m] = *(const s16x8*)&sA[(wm + m * 16 + lr) * 64 + (((kc * 4 + lg) ^ (lr & 7)) * 8)];
#pragma unroll
      for (int n = 0; n < 4; ++n)
        bf[n] = *(const s16x8*)&sB[(wn + n * 16 + lr) * 64 + (((kc * 4 + lg) ^ (lr & 7)) * 8)];
#pragma unroll
      for (int m = 0; m < 4; ++m)
#pragma unroll
        for (int n = 0; n < 4; ++n)
          acc[m][n] = __builtin_amdgcn_mfma_f32_16x16x32_bf16(af[m], bf[n], acc[m][n], 0, 0, 0);
    }
    __syncthreads();
  }

#pragma unroll
  for (int m = 0; m < 4; ++m) {
#pragma unroll
    for (int n = 0; n < 4; ++n) {
#pragma unroll
      for (int r = 0; r < 4; ++r) {
        int row = m0 + wm + m * 16 + (lg << 2) + r;
        int col = n0 + wn + n * 16 + lr;
        float val = acc[m][n][r];
        if (mode == 0) {
          val += bias[col];
          int b = row >> 11, s = row & 2047;
          u16 bvv = f2bf(val);
          if (col < 2048) {
            int h = col >> 7, d = col & 127;
            Qp[(((size_t)(b * 16 + h)) * 2048 + s) * 128 + d] = bvv;
          } else if (col < 2560) {
            int cc = col - 2048; int kh = cc >> 7, d = cc & 127;
            Kp[(((size_t)(b * 4 + kh)) * 2048 + s) * 128 + d] = bvv;
          } else {
            int cc = col - 2560; int kh = cc >> 7, d = cc & 127;
            Vp[(((size_t)(b * 4 + kh)) * 2048 + s) * 128 + d] = bvv;
          }
        } else {
          C[(size_t)row * ldc + col] = val;
        }
      }
    }
  }
}

// ---------------- MFMA flash attention v6 (causal, GQA, 2-phase prefetch, T5) ------
// Q: [B*16][S][128] bf16 (rope'd), K: [B*4][S][128] bf16 (rope'd), Vt: [B*4][128][S]
// O (att): [B,S,2048] bf16.  grid = (32, 32), block = 256 (4 waves).
// Block q-tile = 64 rows, heavy-first (qc = 31 - by); wave w owns rows qw=q0+w*16..+15.
// KV tile = 64, double-buffered; one __syncthreads per step (drains vmcnt).
// K/Vt staged with pre-swizzled global chunk (cc ^= row&7); reads apply same XOR.
// Softmax: exp2-domain, defer-max THR=8, per-lane partial denominator.
// s_setprio(1) wraps the MFMA clusters (T5; 2 blocks/CU at different phases).
__global__ __launch_bounds__(256) void flash_mfma_kernel(const u16* __restrict__ Q,
                                                         const u16* __restrict__ Kb,
                                                         const u16* __restrict__ Vtb,
                                                         u16* __restrict__ O) {
  const int S = 2048;
  __shared__ u16 sK[2 * 64 * 128];   // [buf][j][d], 16B-chunk XOR (j&7)
  __shared__ u16 sVt[2 * 128 * 64];  // [buf][d][j], 16B-chunk XOR (d&7)
  __shared__ u16 sP[4 * 16 * 76];    // per-wave P slabs, stride 76

  const int t = threadIdx.x, w = t >> 6, l = t & 63;
  const int lg = l >> 4, lr = l & 15;
  const int bh = blockIdx.x, b = bh >> 4, h = bh & 15, kvh = h >> 2;
  const int qc = 31 - blockIdx.y;            // heavy blocks dispatch first
  const int q0 = qc * 64;
  const int qw = q0 + w * 16;

  const u16* qbase = Q + ((size_t)bh * S + qw) * 128;
  const u16* kbase = Kb + ((size_t)(b * 4 + kvh)) * S * 128;
  const u16* vtbase = Vtb + ((size_t)(b * 4 + kvh)) * 128 * S;

  // Q fragments: qa[kc][e] = Q[qw + lr][kc*32 + lg*8 + e]
  s16x8 qa[4];
#pragma unroll
  for (int kc = 0; kc < 4; ++kc)
    qa[kc] = *(const s16x8*)&qbase[(size_t)lr * 128 + kc * 32 + lg * 8];

  f32x4 o[8];
#pragma unroll
  for (int dt = 0; dt < 8; ++dt)
#pragma unroll
    for (int r = 0; r < 4; ++r) o[dt][r] = 0.0f;
  float mrun[4], lsum[4];   // lsum is a PER-LANE partial (this lane's 4 columns)
#pragma unroll
  for (int r = 0; r < 4; ++r) { mrun[r] = -3e38f; lsum[r] = 0.0f; }

  u16* sPw = &sP[w * 16 * 76];
  const float C2 = 0.12753785f;   // (1/sqrt(128)) * log2(e)
  const int nt = qc + 1;

  // staging helpers: per-wave quarter, source-swizzled, wave-linear LDS dest
  auto stage = [&](int kt, int buf) {
#pragma unroll
    for (int i = 0; i < 4; ++i) {
      int c = w * 256 + i * 64 + l;
      int j = c >> 4, cc = (c & 15) ^ (j & 7);
      load_lds16(kbase + ((size_t)(kt * 64 + j) * 128 + cc * 8),
                 (char*)sK + buf * 16384 + (w * 4096 + i * 1024));
    }
#pragma unroll
    for (int i = 0; i < 4; ++i) {
      int c = w * 256 + i * 64 + l;
      int d = c >> 3, cc = (c & 7) ^ (d & 7);
      load_lds16(vtbase + ((size_t)d * S + kt * 64 + cc * 8),
                 (char*)sVt + buf * 16384 + (w * 4096 + i * 1024));
    }
  };

  stage(0, 0);
  __syncthreads();   // drains vmcnt -> buf0 ready

  int cur = 0;
  for (int kt = 0; kt < nt; ++kt) {
    if (kt + 1 < nt) stage(kt + 1, cur ^ 1);   // prefetch next tile (overlaps compute)

    const u16* sKc = &sK[cur * 8192];
    const u16* sVc = &sVt[cur * 8192];

    // ---- QK^T: 16 MFMA ----
    f32x4 sc[4];
#pragma unroll
    for (int n = 0; n < 4; ++n)
#pragma unroll
      for (int r = 0; r < 4; ++r) sc[n][r] = 0.0f;
    __builtin_amdgcn_s_setprio(1);
#pragma unroll
    for (int n = 0; n < 4; ++n) {
      int j = n * 16 + lr;
#pragma unroll
      for (int kc = 0; kc < 4; ++kc) {
        s16x8 kf = *(const s16x8*)&sKc[j * 128 + (((kc * 4 + lg) ^ (lr & 7)) * 8)];
        sc[n] = __builtin_amdgcn_mfma_f32_16x16x32_bf16(qa[kc], kf, sc[n], 0, 0, 0);
      }
    }
    __builtin_amdgcn_s_setprio(0);

    // ---- online softmax (exp2 domain, defer-max THR=8, per-lane lsum) ----
    const bool needmask = (kt * 64 + 63 > qw);
#pragma unroll
    for (int r = 0; r < 4; ++r) {
      float a0 = sc[0][r], a1 = sc[1][r], a2 = sc[2][r], a3 = sc[3][r];
      if (needmask) {
        int qi = qw + lg * 4 + r;
        int j0 = kt * 64 + lr;
        a0 = (j0 <= qi) ? a0 : -3e38f;
        a1 = (j0 + 16 <= qi) ? a1 : -3e38f;
        a2 = (j0 + 32 <= qi) ? a2 : -3e38f;
        a3 = (j0 + 48 <= qi) ? a3 : -3e38f;
      }
      float mt = fmaxf(fmaxf(a0, a1), fmaxf(a2, a3));
#pragma unroll
      for (int off = 1; off < 16; off <<= 1) mt = fmaxf(mt, __shfl_xor(mt, off));
      float mt2 = mt * C2;
      float M = mrun[r];
      bool resc = (mt2 > M + 8.0f);
      float Mn = resc ? mt2 : M;
      float p0 = exp2f(__builtin_fmaf(a0, C2, -Mn));
      float p1 = exp2f(__builtin_fmaf(a1, C2, -Mn));
      float p2 = exp2f(__builtin_fmaf(a2, C2, -Mn));
      float p3 = exp2f(__builtin_fmaf(a3, C2, -Mn));
      float ps = (p0 + p1) + (p2 + p3);
      if (resc) {
        float corr = exp2f(M - Mn);
        lsum[r] = lsum[r] * corr + ps;
        mrun[r] = Mn;
#pragma unroll
        for (int dt = 0; dt < 8; ++dt) o[dt][r] *= corr;
      } else {
        lsum[r] += ps;
      }
      int prow = (lg * 4 + r) * 76;
      sPw[prow + lr]      = f2bf_t(p0);
      sPw[prow + 16 + lr] = f2bf_t(p1);
      sPw[prow + 32 + lr] = f2bf_t(p2);
      sPw[prow + 48 + lr] = f2bf_t(p3);
    }

    // ---- PV: 16 MFMA (wave-local sP dependency) ----
    s16x8 pa0 = *(const s16x8*)&sPw[lr * 76 + lg * 8];
    s16x8 pa1 = *(const s16x8*)&sPw[lr * 76 + 32 + lg * 8];
    __builtin_amdgcn_s_setprio(1);
#pragma unroll
    for (int dt = 0; dt < 8; ++dt) {
      int vrow = (dt * 16 + lr) * 64;
      s16x8 vt0 = *(const s16x8*)&sVc[vrow + ((lg ^ (lr & 7)) * 8)];
      s16x8 vt1 = *(const s16x8*)&sVc[vrow + (((4 + lg) ^ (lr & 7)) * 8)];
      o[dt] = __builtin_amdgcn_mfma_f32_16x16x32_bf16(pa0, vt0, o[dt], 0, 0, 0);
      o[dt] = __builtin_amdgcn_mfma_f32_16x16x32_bf16(pa1, vt1, o[dt], 0, 0, 0);
    }
    __builtin_amdgcn_s_setprio(0);

    __syncthreads();   // drains vmcnt (next buf staged) + protects cur buf reuse
    cur ^= 1;
  }

  // epilogue: reduce per-lane denominators across the row's 16 lanes, normalize, store
#pragma unroll
  for (int r = 0; r < 4; ++r) {
    float ls = lsum[r];
#pragma unroll
    for (int off = 1; off < 16; off <<= 1) ls += __shfl_xor(ls, off);
    float inv = 1.0f / ls;
    int qi = qw + lg * 4 + r;
    size_t base = ((size_t)b * S + qi) * 2048 + h * 128;
#pragma unroll
    for (int dt = 0; dt < 8; ++dt)
      O[base + dt * 16 + lr] = f2bf(o[dt][r] * inv);
  }
}

// ---------------- launch ----------------

extern "C" void kernel_launch(void* const* d_in, const int* in_sizes, int n_in,
                              void* d_out, int out_size, void* d_ws, size_t ws_size,
                              hipStream_t stream) {
  const float* x  = (const float*)d_in[0];
  const float* wq = (const float*)d_in[1];
  const float* bq = (const float*)d_in[2];
  const float* wk = (const float*)d_in[3];
  const float* bk = (const float*)d_in[4];
  const float* wv = (const float*)d_in[5];
  const float* bv = (const float*)d_in[6];
  const float* wo = (const float*)d_in[7];
  float* out = (float*)d_out;

  char* ws = (char*)d_ws;
  u16* xb    = (u16*)ws;    ws += (size_t)4096 * 2048 * 2;
  u16* wqkv  = (u16*)ws;    ws += (size_t)3072 * 2048 * 2;
  float* bqkv = (float*)ws; ws += (size_t)3072 * 4;
  u16* wob   = (u16*)ws;    ws += (size_t)2048 * 2048 * 2;
  u16* Qb    = (u16*)ws;    ws += (size_t)32 * 2048 * 128 * 2;
  u16* Kbuf  = (u16*)ws;    ws += (size_t)8 * 2048 * 128 * 2;
  u16* Vbuf  = (u16*)ws;    ws += (size_t)8 * 2048 * 128 * 2;
  u16* Vt    = (u16*)ws;    ws += (size_t)8 * 128 * 2048 * 2;
  float* cosb = (float*)ws; ws += (size_t)2048 * 64 * 4;
  float* sinb = (float*)ws; ws += (size_t)2048 * 64 * 4;
  u16* att   = (u16*)ws;    ws += (size_t)4096 * 2048 * 2;

  cast_bf16_kernel<<<8192, 256, 0, stream>>>(x, xb, 4096 * 2048 / 4);
  pack_qkv_w_kernel<<<6144, 256, 0, stream>>>(wq, wk, wv, wqkv);
  pack_bias_kernel<<<12, 256, 0, stream>>>(bq, bk, bv, bqkv);
  cast_bf16_kernel<<<4096, 256, 0, stream>>>(wo, wob, 2048 * 2048 / 4);
  rope_table_kernel<<<512, 256, 0, stream>>>(cosb, sinb);

  gemm_bt_kernel<<<dim3(24, 32), 256, 0, stream>>>(xb, wqkv, bqkv, nullptr, 0,
                                                   Qb, Kbuf, Vbuf, 4096, 3072, 2048, 0);
  transpose_v_kernel<<<dim3(8, 32), 256, 0, stream>>>(Vbuf, Vt);
  rope_kernel<<<16384, 256, 0, stream>>>(Qb, cosb, sinb, 32 * 2048 * 64);
  rope_kernel<<<4096, 256, 0, stream>>>(Kbuf, cosb, sinb, 8 * 2048 * 64);

  flash_mfma_kernel<<<dim3(32, 32), 256, 0, stream>>>(Qb, Kbuf, Vt, att);

  gemm_bt_kernel<<<dim3(16, 32), 256, 0, stream>>>(att, wob, nullptr, out, 2048,
                                                   nullptr, nullptr, nullptr, 4096, 2048, 2048, 1);
}

// Round 7
// 274.978 us; speedup vs baseline: 1.1389x; 1.0687x over previous
//
#include <hip/hip_runtime.h>

typedef unsigned short u16;
typedef short s16x8 __attribute__((ext_vector_type(8)));
typedef float f32x4 __attribute__((ext_vector_type(4)));
typedef float f32x16 __attribute__((ext_vector_type(16)));

__device__ __forceinline__ u16 f2bf(float f) {
  union { float f; unsigned u; } x; x.f = f;
  unsigned r = (x.u + 0x7fffu + ((x.u >> 16) & 1u)) >> 16;
  return (u16)r;
}
__device__ __forceinline__ unsigned bfbits_t(float f) {   // truncating, as u32 low bits
  union { float f; unsigned u; } x; x.f = f;
  return x.u >> 16;
}
__device__ __forceinline__ float bf2f(u16 u) {
  union { unsigned u; float f; } x; x.u = ((unsigned)u) << 16;
  return x.f;
}

__device__ __forceinline__ void load_lds16(const u16* g, void* lds) {
  __builtin_amdgcn_global_load_lds(
      (const __attribute__((address_space(1))) unsigned int*)g,
      (__attribute__((address_space(3))) unsigned int*)lds, 16, 0, 0);
}

// ---------------- prep kernels ----------------

__global__ __launch_bounds__(256) void cast_bf16_kernel(const float* __restrict__ src,
                                                        u16* __restrict__ dst, int n4) {
  int id = blockIdx.x * 256 + threadIdx.x;
  if (id >= n4) return;
  float4 v = ((const float4*)src)[id];
  u16* d = dst + (size_t)id * 4;
  d[0] = f2bf(v.x); d[1] = f2bf(v.y); d[2] = f2bf(v.z); d[3] = f2bf(v.w);
}

__global__ __launch_bounds__(256) void pack_qkv_w_kernel(const float* __restrict__ wq,
                                                         const float* __restrict__ wk,
                                                         const float* __restrict__ wv,
                                                         u16* __restrict__ dst) {
  int id = blockIdx.x * 256 + threadIdx.x;   // over 3072*512 float4 groups
  if (id >= 3072 * 512) return;
  int row = id >> 9;
  int c4 = (id & 511) * 4;
  const float* src; int srow;
  if (row < 2048)      { src = wq; srow = row; }
  else if (row < 2560) { src = wk; srow = row - 2048; }
  else                 { src = wv; srow = row - 2560; }
  float4 v = *(const float4*)&src[(size_t)srow * 2048 + c4];
  u16* d = dst + (size_t)row * 2048 + c4;
  d[0] = f2bf(v.x); d[1] = f2bf(v.y); d[2] = f2bf(v.z); d[3] = f2bf(v.w);
}

__global__ __launch_bounds__(256) void pack_bias_kernel(const float* __restrict__ bq,
                                                        const float* __restrict__ bk,
                                                        const float* __restrict__ bv,
                                                        float* __restrict__ dst) {
  int id = blockIdx.x * 256 + threadIdx.x;
  if (id >= 3072) return;
  float v;
  if (id < 2048)      v = bq[id];
  else if (id < 2560) v = bk[id - 2048];
  else                v = bv[id - 2560];
  dst[id] = v;
}

__global__ __launch_bounds__(256) void rope_table_kernel(float* __restrict__ cosb,
                                                         float* __restrict__ sinb) {
  int id = blockIdx.x * 256 + threadIdx.x;   // S*64 = 131072
  if (id >= 2048 * 64) return;
  int s = id >> 6, i = id & 63;
  float freq = powf(10000.0f, -(float)i / 64.0f);
  float ang = (float)s * freq;
  cosb[id] = cosf(ang);
  sinb[id] = sinf(ang);
}

// in-place RoPE on bf16 buffer laid out [rows][128], rows = NH*S
__global__ __launch_bounds__(256) void rope_kernel(u16* __restrict__ p,
                                                   const float* __restrict__ cosb,
                                                   const float* __restrict__ sinb,
                                                   int total) {
  int id = blockIdx.x * 256 + threadIdx.x;   // total = rows*64
  if (id >= total) return;
  int i = id & 63;
  int rs = id >> 6;
  int s = rs & 2047;                          // S = 2048
  size_t base = (size_t)rs * 128;
  float x1 = bf2f(p[base + i]);
  float x2 = bf2f(p[base + i + 64]);
  float c = cosb[s * 64 + i], sn = sinb[s * 64 + i];
  p[base + i]      = f2bf(x1 * c - x2 * sn);
  p[base + i + 64] = f2bf(x2 * c + x1 * sn);
}

// V [8][2048][128] -> Vt [8][128][2048]
__global__ __launch_bounds__(256) void transpose_v_kernel(const u16* __restrict__ V,
                                                          u16* __restrict__ Vt) {
  __shared__ u16 tile[64][130];
  const int t = threadIdx.x;
  const int hb = blockIdx.x, s0 = blockIdx.y * 64;
  const u16* src = V + ((size_t)hb * 2048 + s0) * 128;
#pragma unroll
  for (int i = 0; i < 4; ++i) {
    int c = i * 256 + t;            // 0..1023
    int s = c >> 4, d8 = (c & 15) * 8;
    *(s16x8*)&tile[s][d8] = *(const s16x8*)&src[(size_t)s * 128 + d8];
  }
  __syncthreads();
  u16* dst = Vt + (size_t)hb * 128 * 2048 + s0;
#pragma unroll
  for (int i = 0; i < 4; ++i) {
    int c = i * 256 + t;
    int d = c & 127, s8 = (c >> 7) * 8;
    s16x8 v;
#pragma unroll
    for (int e = 0; e < 8; ++e) v[e] = (short)tile[s8 + e][d];
    *(s16x8*)&dst[(size_t)d * 2048 + s8] = v;
  }
}

// ---------------- bf16 MFMA GEMM, BK=64, T2-swizzled LDS, T1 XCD block swizzle ----
// C[m,n] = sum_k A[m,k]*B[n,k] (+bias)
// mode 0: scatter to Q/K/V bf16 buffers (+bias). mode 1: plain f32 C.
__global__ __launch_bounds__(256) void gemm_bt_kernel(
    const u16* __restrict__ A, const u16* __restrict__ Bw,
    const float* __restrict__ bias,
    float* __restrict__ C, int ldc,
    u16* __restrict__ Qp, u16* __restrict__ Kp, u16* __restrict__ Vp,
    int M, int N, int K, int mode) {
  __shared__ u16 sA[128 * 64];   // 16 KB
  __shared__ u16 sB[128 * 64];   // 16 KB
  const int t = threadIdx.x;
  const int w = t >> 6, l = t & 63;
  const int lg = l >> 4, lr = l & 15;
  const int wm = (w >> 1) * 64, wn = (w & 1) * 64;

  // T1: XCD-aware block swizzle (nwg % 8 == 0 for both grids used)
  const int nwg = gridDim.x * gridDim.y;
  const int id = blockIdx.y * gridDim.x + blockIdx.x;
  const int swz = (id & 7) * (nwg >> 3) + (id >> 3);
  const int m0 = (swz / gridDim.x) * 128, n0 = (swz % gridDim.x) * 128;

  f32x4 acc[4][4];
#pragma unroll
  for (int i = 0; i < 4; ++i)
#pragma unroll
    for (int j = 0; j < 4; ++j)
#pragma unroll
      for (int r = 0; r < 4; ++r) acc[i][j][r] = 0.0f;

  for (int k0 = 0; k0 < K; k0 += 64) {
#pragma unroll
    for (int i = 0; i < 4; ++i) {
      int c = i * 256 + t;                 // dest byte = c*16 = i*4096 + w*1024 + l*16
      int row = c >> 3, cc = (c & 7) ^ (row & 7);
      load_lds16(A + (size_t)(m0 + row) * K + k0 + cc * 8,
                 (char*)sA + i * 4096 + w * 1024);
      load_lds16(Bw + (size_t)(n0 + row) * K + k0 + cc * 8,
                 (char*)sB + i * 4096 + w * 1024);
    }
    __syncthreads();
#pragma unroll
    for (int kc = 0; kc < 2; ++kc) {
      s16x8 af[4], bf[4];
#pragma unroll
      for (int m = 0; m < 4; ++m)
        af[m] = *(const s16x8*)&sA[(wm + m * 16 + lr) * 64 + (((kc * 4 + lg) ^ (lr & 7)) * 8)];
#pragma unroll
      for (int n = 0; n < 4; ++n)
        bf[n] = *(const s16x8*)&sB[(wn + n * 16 + lr) * 64 + (((kc * 4 + lg) ^ (lr & 7)) * 8)];
#pragma unroll
      for (int m = 0; m < 4; ++m)
#pragma unroll
        for (int n = 0; n < 4; ++n)
          acc[m][n] = __builtin_amdgcn_mfma_f32_16x16x32_bf16(af[m], bf[n], acc[m][n], 0, 0, 0);
    }
    __syncthreads();
  }

#pragma unroll
  for (int m = 0; m < 4; ++m) {
#pragma unroll
    for (int n = 0; n < 4; ++n) {
#pragma unroll
      for (int r = 0; r < 4; ++r) {
        int row = m0 + wm + m * 16 + (lg << 2) + r;
        int col = n0 + wn + n * 16 + lr;
        float val = acc[m][n][r];
        if (mode == 0) {
          val += bias[col];
          int b = row >> 11, s = row & 2047;
          u16 bvv = f2bf(val);
          if (col < 2048) {
            int h = col >> 7, d = col & 127;
            Qp[(((size_t)(b * 16 + h)) * 2048 + s) * 128 + d] = bvv;
          } else if (col < 2560) {
            int cc = col - 2048; int kh = cc >> 7, d = cc & 127;
            Kp[(((size_t)(b * 4 + kh)) * 2048 + s) * 128 + d] = bvv;
          } else {
            int cc = col - 2560; int kh = cc >> 7, d = cc & 127;
            Vp[(((size_t)(b * 4 + kh)) * 2048 + s) * 128 + d] = bvv;
          }
        } else {
          C[(size_t)row * ldc + col] = val;
        }
      }
    }
  }
}

// ---------------- MFMA flash attention v7: 32x32 swapped-operand, in-register P ----
// Q: [B*16][S][128] bf16 (rope'd), K: [B*4][S][128] bf16 (rope'd), Vt: [B*4][128][S]
// O (att): [B,S,2048] bf16.  grid = (32, 16), block = 256 (4 waves).
// Block q-tile = 128 (heavy-first qc = 15 - by); wave w owns 32 q-rows qw..qw+31.
// KV tile = 64, double-buffered (64 KB LDS -> 2 blocks/CU, grid = exactly 2/CU).
// QK^T swapped: sc = mfma32(K, Q) -> lane's col = q (lane&31), rows = j.
// Softmax per-lane q: local 32-reg reduce + one shfl_xor(32). P packed to bf16
// in-register; j-halves exchanged with lane^32 (T12 via shfl); PV = mfma32(Vt, P)
// keeps O col = q, so corr/lsum stay lane-local. No P LDS round-trip.
// Layouts: C/D col=lane&31, row=(r&3)+8*(r>>2)+4*(lane>>5) [m74/m101];
// A/B row(col)=lane&31, k=(lane>>5)*8+e (extrapolated from verified 16x16 pattern).
__global__ __launch_bounds__(256) void flash_mfma_kernel(const u16* __restrict__ Q,
                                                         const u16* __restrict__ Kb,
                                                         const u16* __restrict__ Vtb,
                                                         u16* __restrict__ O) {
  const int S = 2048;
  __shared__ u16 sK[2 * 64 * 128];   // [buf][j][d], 16B-chunk XOR (j&7)
  __shared__ u16 sVt[2 * 128 * 64];  // [buf][d][j], 16B-chunk XOR (d&7)

  const int t = threadIdx.x, w = t >> 6, l = t & 63;
  const int l31 = l & 31, hi = l >> 5;
  const int bh = blockIdx.x, b = bh >> 4, h = bh & 15, kvh = h >> 2;
  const int qc = 15 - blockIdx.y;            // heavy blocks dispatch first
  const int q0 = qc * 128;
  const int qw = q0 + w * 32;

  const u16* qbase = Q + ((size_t)bh * S + qw) * 128;
  const u16* kbase = Kb + ((size_t)(b * 4 + kvh)) * S * 128;
  const u16* vtbase = Vtb + ((size_t)(b * 4 + kvh)) * 128 * S;

  // Q (B-operand) in regs: qb[ks][e] = Q[qw + l31][ks*16 + hi*8 + e], ks = 0..7
  s16x8 qb[8];
#pragma unroll
  for (int ks = 0; ks < 8; ++ks)
    qb[ks] = *(const s16x8*)&qbase[(size_t)l31 * 128 + ks * 16 + hi * 8];

  f32x16 o0, o1, o2, o3;   // o[dt]: row d = (r&3)+8*(r>>2)+4*hi + 32*dt, col q = l31
#pragma unroll
  for (int r = 0; r < 16; ++r) { o0[r] = 0.f; o1[r] = 0.f; o2[r] = 0.f; o3[r] = 0.f; }
  float mrun = -3e38f, lsum = 0.0f;   // per-lane (q = l31); lane^32 holds partner half

  const float C2 = 0.12753785f;   // (1/sqrt(128)) * log2(e)
  const int nt = qc * 2 + 2;
  const int q_glob = qw + l31;

  auto stage = [&](int kt, int buf) {
#pragma unroll
    for (int i = 0; i < 4; ++i) {
      int c = w * 256 + i * 64 + l;
      int j = c >> 4, cc = (c & 15) ^ (j & 7);
      load_lds16(kbase + ((size_t)(kt * 64 + j) * 128 + cc * 8),
                 (char*)sK + buf * 16384 + (w * 4096 + i * 1024));
    }
#pragma unroll
    for (int i = 0; i < 4; ++i) {
      int c = w * 256 + i * 64 + l;
      int d = c >> 3, cc = (c & 7) ^ (d & 7);
      load_lds16(vtbase + ((size_t)d * S + kt * 64 + cc * 8),
                 (char*)sVt + buf * 16384 + (w * 4096 + i * 1024));
    }
  };

  stage(0, 0);
  __syncthreads();

  int cur = 0;
  for (int kt = 0; kt < nt; ++kt) {
    if (kt + 1 < nt) stage(kt + 1, cur ^ 1);   // prefetch overlaps compute

    if (kt * 64 <= qw + 31) {
      const u16* sKc = &sK[cur * 8192];
      const u16* sVc = &sVt[cur * 8192];

      // ---- QK^T swapped: sc[jb] = K[jb-tile] x Q, 16 MFMA ----
      f32x16 sc0, sc1;
#pragma unroll
      for (int r = 0; r < 16; ++r) { sc0[r] = 0.f; sc1[r] = 0.f; }
#pragma unroll
      for (int ks = 0; ks < 8; ++ks) {
        int chk = (2 * ks + hi) ^ (l31 & 7);        // same XOR for j and j+32
        s16x8 kf0 = *(const s16x8*)&sKc[l31 * 128 + chk * 8];
        s16x8 kf1 = *(const s16x8*)&sKc[(32 + l31) * 128 + chk * 8];
        sc0 = __builtin_amdgcn_mfma_f32_32x32x16_bf16(kf0, qb[ks], sc0, 0, 0, 0);
        sc1 = __builtin_amdgcn_mfma_f32_32x32x16_bf16(kf1, qb[ks], sc1, 0, 0, 0);
      }

      // ---- causal mask (diagonal tiles only) ----
      if (kt * 64 + 63 > qw) {
        const int j0 = kt * 64;
#pragma unroll
        for (int r = 0; r < 16; ++r) {
          int jr = j0 + (r & 3) + 8 * (r >> 2) + 4 * hi;
          sc0[r] = (jr <= q_glob) ? sc0[r] : -3e38f;
          sc1[r] = (jr + 32 <= q_glob) ? sc1[r] : -3e38f;
        }
      }

      // ---- online softmax (per-lane q, exp2 domain, defer-max THR=8) ----
      float mt = -3e38f;
#pragma unroll
      for (int r = 0; r < 16; ++r) mt = fmaxf(mt, fmaxf(sc0[r], sc1[r]));
      mt = fmaxf(mt, __shfl_xor(mt, 32));
      float mt2 = mt * C2;
      bool resc = (mt2 > mrun + 8.0f);
      if (resc) {
        float Mn = mt2;
        float corr = exp2f(mrun - Mn);
        lsum *= corr;
#pragma unroll
        for (int r = 0; r < 16; ++r) {
          o0[r] *= corr; o1[r] *= corr; o2[r] *= corr; o3[r] *= corr;
        }
        mrun = Mn;
      }
      const float Mn = mrun;

      // p = exp2(sc*C2 - Mn), packed to bf16 pairs; pk[jb*8+m] covers j' pair
      unsigned pk[16];
      float lacc = 0.0f;
#pragma unroll
      for (int m = 0; m < 8; ++m) {
        float pa_ = exp2f(__builtin_fmaf(sc0[2 * m], C2, -Mn));
        float pb_ = exp2f(__builtin_fmaf(sc0[2 * m + 1], C2, -Mn));
        lacc += pa_ + pb_;
        pk[m] = (bfbits_t(pb_) << 16) | bfbits_t(pa_);
      }
#pragma unroll
      for (int m = 0; m < 8; ++m) {
        float pa_ = exp2f(__builtin_fmaf(sc1[2 * m], C2, -Mn));
        float pb_ = exp2f(__builtin_fmaf(sc1[2 * m + 1], C2, -Mn));
        lacc += pa_ + pb_;
        pk[8 + m] = (bfbits_t(pb_) << 16) | bfbits_t(pa_);
      }
      lsum += lacc;

      // exchange j-halves with partner lane (l ^ 32)
      unsigned pkx[16];
#pragma unroll
      for (int i = 0; i < 16; ++i) pkx[i] = __shfl_xor(pk[i], 32);

      // ---- PV: o[dt] += Vt-frag x P-frag, 16 MFMA ----
#pragma unroll
      for (int ks = 0; ks < 4; ++ks) {
        const int base = (ks >> 1) * 8 + 4 * (ks & 1);
        unsigned pw[4];
        pw[0] = hi ? pkx[base + 2] : pk[base + 0];
        pw[1] = hi ? pkx[base + 3] : pk[base + 1];
        pw[2] = hi ? pk[base + 2] : pkx[base + 0];
        pw[3] = hi ? pk[base + 3] : pkx[base + 1];
        s16x8 pa = *(const s16x8*)pw;
#pragma unroll
        for (int dt = 0; dt < 4; ++dt) {
          int d = dt * 32 + l31;
          s16x8 vt = *(const s16x8*)&sVc[d * 64 + (((2 * ks + hi) ^ (d & 7)) * 8)];
          if (dt == 0) o0 = __builtin_amdgcn_mfma_f32_32x32x16_bf16(vt, pa, o0, 0, 0, 0);
          if (dt == 1) o1 = __builtin_amdgcn_mfma_f32_32x32x16_bf16(vt, pa, o1, 0, 0, 0);
          if (dt == 2) o2 = __builtin_amdgcn_mfma_f32_32x32x16_bf16(vt, pa, o2, 0, 0, 0);
          if (dt == 3) o3 = __builtin_amdgcn_mfma_f32_32x32x16_bf16(vt, pa, o3, 0, 0, 0);
        }
      }
    }

    __syncthreads();   // drains vmcnt (next buf staged) + protects cur buf reuse
    cur ^= 1;
  }

  // ---- epilogue: denominator (2-lane reduce), normalize, packed stores ----
  float ls = lsum + __shfl_xor(lsum, 32);
  float inv = 1.0f / ls;
  size_t obase = ((size_t)b * S + q_glob) * 2048 + h * 128;
#pragma unroll
  for (int dt = 0; dt < 4; ++dt) {
    const f32x16& ov = (dt == 0) ? o0 : (dt == 1) ? o1 : (dt == 2) ? o2 : o3;
#pragma unroll
    for (int g = 0; g < 4; ++g) {
      int d0 = dt * 32 + 8 * g + 4 * hi;
      unsigned u0 = (unsigned)f2bf(ov[4 * g] * inv) | ((unsigned)f2bf(ov[4 * g + 1] * inv) << 16);
      unsigned u1 = (unsigned)f2bf(ov[4 * g + 2] * inv) | ((unsigned)f2bf(ov[4 * g + 3] * inv) << 16);
      uint2 u; u.x = u0; u.y = u1;
      *(uint2*)&O[obase + d0] = u;
    }
  }
}

// ---------------- launch ----------------

extern "C" void kernel_launch(void* const* d_in, const int* in_sizes, int n_in,
                              void* d_out, int out_size, void* d_ws, size_t ws_size,
                              hipStream_t stream) {
  const float* x  = (const float*)d_in[0];
  const float* wq = (const float*)d_in[1];
  const float* bq = (const float*)d_in[2];
  const float* wk = (const float*)d_in[3];
  const float* bk = (const float*)d_in[4];
  const float* wv = (const float*)d_in[5];
  const float* bv = (const float*)d_in[6];
  const float* wo = (const float*)d_in[7];
  float* out = (float*)d_out;

  char* ws = (char*)d_ws;
  u16* xb    = (u16*)ws;    ws += (size_t)4096 * 2048 * 2;
  u16* wqkv  = (u16*)ws;    ws += (size_t)3072 * 2048 * 2;
  float* bqkv = (float*)ws; ws += (size_t)3072 * 4;
  u16* wob   = (u16*)ws;    ws += (size_t)2048 * 2048 * 2;
  u16* Qb    = (u16*)ws;    ws += (size_t)32 * 2048 * 128 * 2;
  u16* Kbuf  = (u16*)ws;    ws += (size_t)8 * 2048 * 128 * 2;
  u16* Vbuf  = (u16*)ws;    ws += (size_t)8 * 2048 * 128 * 2;
  u16* Vt    = (u16*)ws;    ws += (size_t)8 * 128 * 2048 * 2;
  float* cosb = (float*)ws; ws += (size_t)2048 * 64 * 4;
  float* sinb = (float*)ws; ws += (size_t)2048 * 64 * 4;
  u16* att   = (u16*)ws;    ws += (size_t)4096 * 2048 * 2;

  cast_bf16_kernel<<<8192, 256, 0, stream>>>(x, xb, 4096 * 2048 / 4);
  pack_qkv_w_kernel<<<6144, 256, 0, stream>>>(wq, wk, wv, wqkv);
  pack_bias_kernel<<<12, 256, 0, stream>>>(bq, bk, bv, bqkv);
  cast_bf16_kernel<<<4096, 256, 0, stream>>>(wo, wob, 2048 * 2048 / 4);
  rope_table_kernel<<<512, 256, 0, stream>>>(cosb, sinb);

  gemm_bt_kernel<<<dim3(24, 32), 256, 0, stream>>>(xb, wqkv, bqkv, nullptr, 0,
                                                   Qb, Kbuf, Vbuf, 4096, 3072, 2048, 0);
  transpose_v_kernel<<<dim3(8, 32), 256, 0, stream>>>(Vbuf, Vt);
  rope_kernel<<<16384, 256, 0, stream>>>(Qb, cosb, sinb, 32 * 2048 * 64);
  rope_kernel<<<4096, 256, 0, stream>>>(Kbuf, cosb, sinb, 8 * 2048 * 64);

  flash_mfma_kernel<<<dim3(32, 16), 256, 0, stream>>>(Qb, Kbuf, Vt, att);

  gemm_bt_kernel<<<dim3(16, 32), 256, 0, stream>>>(att, wob, nullptr, out, 2048,
                                                   nullptr, nullptr, nullptr, 4096, 2048, 2048, 1);
}

// Round 8
// 269.934 us; speedup vs baseline: 1.1601x; 1.0187x over previous
//
#include <hip/hip_runtime.h>

typedef unsigned short u16;
typedef short s16x8 __attribute__((ext_vector_type(8)));
typedef float f32x4 __attribute__((ext_vector_type(4)));
typedef float f32x16 __attribute__((ext_vector_type(16)));

__device__ __forceinline__ u16 f2bf(float f) {
  union { float f; unsigned u; } x; x.f = f;
  unsigned r = (x.u + 0x7fffu + ((x.u >> 16) & 1u)) >> 16;
  return (u16)r;
}
__device__ __forceinline__ unsigned bfbits_t(float f) {   // truncating, as u32 low bits
  union { float f; unsigned u; } x; x.f = f;
  return x.u >> 16;
}
__device__ __forceinline__ float bf2f(u16 u) {
  union { unsigned u; float f; } x; x.u = ((unsigned)u) << 16;
  return x.f;
}

__device__ __forceinline__ void load_lds16(const u16* g, void* lds) {
  __builtin_amdgcn_global_load_lds(
      (const __attribute__((address_space(1))) unsigned int*)g,
      (__attribute__((address_space(3))) unsigned int*)lds, 16, 0, 0);
}

// ---------------- prep kernels ----------------

__global__ __launch_bounds__(256) void cast_bf16_kernel(const float* __restrict__ src,
                                                        u16* __restrict__ dst, int n4) {
  int id = blockIdx.x * 256 + threadIdx.x;
  if (id >= n4) return;
  float4 v = ((const float4*)src)[id];
  u16* d = dst + (size_t)id * 4;
  d[0] = f2bf(v.x); d[1] = f2bf(v.y); d[2] = f2bf(v.z); d[3] = f2bf(v.w);
}

__global__ __launch_bounds__(256) void pack_qkv_w_kernel(const float* __restrict__ wq,
                                                         const float* __restrict__ wk,
                                                         const float* __restrict__ wv,
                                                         u16* __restrict__ dst) {
  int id = blockIdx.x * 256 + threadIdx.x;   // over 3072*512 float4 groups
  if (id >= 3072 * 512) return;
  int row = id >> 9;
  int c4 = (id & 511) * 4;
  const float* src; int srow;
  if (row < 2048)      { src = wq; srow = row; }
  else if (row < 2560) { src = wk; srow = row - 2048; }
  else                 { src = wv; srow = row - 2560; }
  float4 v = *(const float4*)&src[(size_t)srow * 2048 + c4];
  u16* d = dst + (size_t)row * 2048 + c4;
  d[0] = f2bf(v.x); d[1] = f2bf(v.y); d[2] = f2bf(v.z); d[3] = f2bf(v.w);
}

__global__ __launch_bounds__(256) void pack_bias_kernel(const float* __restrict__ bq,
                                                        const float* __restrict__ bk,
                                                        const float* __restrict__ bv,
                                                        float* __restrict__ dst) {
  int id = blockIdx.x * 256 + threadIdx.x;
  if (id >= 3072) return;
  float v;
  if (id < 2048)      v = bq[id];
  else if (id < 2560) v = bk[id - 2048];
  else                v = bv[id - 2560];
  dst[id] = v;
}

__global__ __launch_bounds__(256) void rope_table_kernel(float* __restrict__ cosb,
                                                         float* __restrict__ sinb) {
  int id = blockIdx.x * 256 + threadIdx.x;   // S*64 = 131072
  if (id >= 2048 * 64) return;
  int s = id >> 6, i = id & 63;
  float freq = powf(10000.0f, -(float)i / 64.0f);
  float ang = (float)s * freq;
  cosb[id] = cosf(ang);
  sinb[id] = sinf(ang);
}

// in-place RoPE on bf16 buffer laid out [rows][128], rows = NH*S
__global__ __launch_bounds__(256) void rope_kernel(u16* __restrict__ p,
                                                   const float* __restrict__ cosb,
                                                   const float* __restrict__ sinb,
                                                   int total) {
  int id = blockIdx.x * 256 + threadIdx.x;   // total = rows*64
  if (id >= total) return;
  int i = id & 63;
  int rs = id >> 6;
  int s = rs & 2047;                          // S = 2048
  size_t base = (size_t)rs * 128;
  float x1 = bf2f(p[base + i]);
  float x2 = bf2f(p[base + i + 64]);
  float c = cosb[s * 64 + i], sn = sinb[s * 64 + i];
  p[base + i]      = f2bf(x1 * c - x2 * sn);
  p[base + i + 64] = f2bf(x2 * c + x1 * sn);
}

// V [8][2048][128] -> Vt [8][128][2048]
__global__ __launch_bounds__(256) void transpose_v_kernel(const u16* __restrict__ V,
                                                          u16* __restrict__ Vt) {
  __shared__ u16 tile[64][130];
  const int t = threadIdx.x;
  const int hb = blockIdx.x, s0 = blockIdx.y * 64;
  const u16* src = V + ((size_t)hb * 2048 + s0) * 128;
#pragma unroll
  for (int i = 0; i < 4; ++i) {
    int c = i * 256 + t;            // 0..1023
    int s = c >> 4, d8 = (c & 15) * 8;
    *(s16x8*)&tile[s][d8] = *(const s16x8*)&src[(size_t)s * 128 + d8];
  }
  __syncthreads();
  u16* dst = Vt + (size_t)hb * 128 * 2048 + s0;
#pragma unroll
  for (int i = 0; i < 4; ++i) {
    int c = i * 256 + t;
    int d = c & 127, s8 = (c >> 7) * 8;
    s16x8 v;
#pragma unroll
    for (int e = 0; e < 8; ++e) v[e] = (short)tile[s8 + e][d];
    *(s16x8*)&dst[(size_t)d * 2048 + s8] = v;
  }
}

// ---------------- bf16 MFMA GEMM, BK=32, 2-way-free chunk swizzle ----------------
// C[m,n] = sum_k A[m,k]*B[n,k] (+bias)
// mode 0: scatter to Q/K/V bf16 buffers (+bias). mode 1: plain f32 C.
// LDS tiles [128][32] (64B rows). Chunk swizzle: chunk' = chunk ^ ((row>>1)&3)
// on BOTH stage-source and fragment read -> a b128 read's 16 lanes cover all
// 8 (parity x chunk) slots twice = 2-way = free [m136]. (row+64) preserves
// (row>>1)&3, so one source chunk serves both row-halves; read-side XOR is
// lane-constant: lg ^ ((lr>>1)&3).
__global__ __launch_bounds__(256) void gemm_bt_kernel(
    const u16* __restrict__ A, const u16* __restrict__ Bw,
    const float* __restrict__ bias,
    float* __restrict__ C, int ldc,
    u16* __restrict__ Qp, u16* __restrict__ Kp, u16* __restrict__ Vp,
    int M, int N, int K, int mode) {
  __shared__ u16 sA[128 * 32];   // 8 KB
  __shared__ u16 sB[128 * 32];   // 8 KB
  const int t = threadIdx.x;
  const int w = t >> 6, l = t & 63;
  const int lg = l >> 4, lr = l & 15;
  const int wm = (w >> 1) * 64, wn = (w & 1) * 64;
  const int m0 = blockIdx.y * 128, n0 = blockIdx.x * 128;
  const int srow = t >> 2;
  const int scol = (((t & 3) ^ ((srow >> 1) & 3))) * 8;   // source-swizzled chunk
  const int rchunk = (lg ^ ((lr >> 1) & 3)) * 8;          // read-side chunk (lane-const)

  f32x4 acc[4][4];
#pragma unroll
  for (int i = 0; i < 4; ++i)
#pragma unroll
    for (int j = 0; j < 4; ++j)
#pragma unroll
      for (int r = 0; r < 4; ++r) acc[i][j][r] = 0.0f;

  const size_t arow0 = (size_t)(m0 + srow) * K;
  const size_t arow1 = (size_t)(m0 + 64 + srow) * K;
  const size_t brow0 = (size_t)(n0 + srow) * K;
  const size_t brow1 = (size_t)(n0 + 64 + srow) * K;
  char* ldsA = (char*)sA + (size_t)w * 1024;
  char* ldsB = (char*)sB + (size_t)w * 1024;

  for (int k0 = 0; k0 < K; k0 += 32) {
    load_lds16(A + arow0 + k0 + scol, ldsA);
    load_lds16(A + arow1 + k0 + scol, ldsA + 4096);
    load_lds16(Bw + brow0 + k0 + scol, ldsB);
    load_lds16(Bw + brow1 + k0 + scol, ldsB + 4096);
    __syncthreads();
    s16x8 af[4], bf[4];
#pragma unroll
    for (int m = 0; m < 4; ++m)
      af[m] = *(const s16x8*)&sA[(wm + m * 16 + lr) * 32 + rchunk];
#pragma unroll
    for (int n = 0; n < 4; ++n)
      bf[n] = *(const s16x8*)&sB[(wn + n * 16 + lr) * 32 + rchunk];
#pragma unroll
    for (int m = 0; m < 4; ++m)
#pragma unroll
      for (int n = 0; n < 4; ++n)
        acc[m][n] = __builtin_amdgcn_mfma_f32_16x16x32_bf16(af[m], bf[n], acc[m][n], 0, 0, 0);
    __syncthreads();
  }

#pragma unroll
  for (int m = 0; m < 4; ++m) {
#pragma unroll
    for (int n = 0; n < 4; ++n) {
#pragma unroll
      for (int r = 0; r < 4; ++r) {
        int row = m0 + wm + m * 16 + (lg << 2) + r;
        int col = n0 + wn + n * 16 + lr;
        float val = acc[m][n][r];
        if (mode == 0) {
          val += bias[col];
          int b = row >> 11, s = row & 2047;
          u16 bvv = f2bf(val);
          if (col < 2048) {
            int h = col >> 7, d = col & 127;
            Qp[(((size_t)(b * 16 + h)) * 2048 + s) * 128 + d] = bvv;
          } else if (col < 2560) {
            int cc = col - 2048; int kh = cc >> 7, d = cc & 127;
            Kp[(((size_t)(b * 4 + kh)) * 2048 + s) * 128 + d] = bvv;
          } else {
            int cc = col - 2560; int kh = cc >> 7, d = cc & 127;
            Vp[(((size_t)(b * 4 + kh)) * 2048 + s) * 128 + d] = bvv;
          }
        } else {
          C[(size_t)row * ldc + col] = val;
        }
      }
    }
  }
}

// ---------------- MFMA flash attention v7: 32x32 swapped-operand, in-register P ----
// (unchanged from round 7 — verified correct, ~65 us)
__global__ __launch_bounds__(256) void flash_mfma_kernel(const u16* __restrict__ Q,
                                                         const u16* __restrict__ Kb,
                                                         const u16* __restrict__ Vtb,
                                                         u16* __restrict__ O) {
  const int S = 2048;
  __shared__ u16 sK[2 * 64 * 128];   // [buf][j][d], 16B-chunk XOR (j&7)
  __shared__ u16 sVt[2 * 128 * 64];  // [buf][d][j], 16B-chunk XOR (d&7)

  const int t = threadIdx.x, w = t >> 6, l = t & 63;
  const int l31 = l & 31, hi = l >> 5;
  const int bh = blockIdx.x, b = bh >> 4, h = bh & 15, kvh = h >> 2;
  const int qc = 15 - blockIdx.y;            // heavy blocks dispatch first
  const int q0 = qc * 128;
  const int qw = q0 + w * 32;

  const u16* qbase = Q + ((size_t)bh * S + qw) * 128;
  const u16* kbase = Kb + ((size_t)(b * 4 + kvh)) * S * 128;
  const u16* vtbase = Vtb + ((size_t)(b * 4 + kvh)) * 128 * S;

  // Q (B-operand) in regs: qb[ks][e] = Q[qw + l31][ks*16 + hi*8 + e], ks = 0..7
  s16x8 qb[8];
#pragma unroll
  for (int ks = 0; ks < 8; ++ks)
    qb[ks] = *(const s16x8*)&qbase[(size_t)l31 * 128 + ks * 16 + hi * 8];

  f32x16 o0, o1, o2, o3;   // o[dt]: row d = (r&3)+8*(r>>2)+4*hi + 32*dt, col q = l31
#pragma unroll
  for (int r = 0; r < 16; ++r) { o0[r] = 0.f; o1[r] = 0.f; o2[r] = 0.f; o3[r] = 0.f; }
  float mrun = -3e38f, lsum = 0.0f;   // per-lane (q = l31); lane^32 holds partner half

  const float C2 = 0.12753785f;   // (1/sqrt(128)) * log2(e)
  const int nt = qc * 2 + 2;
  const int q_glob = qw + l31;

  auto stage = [&](int kt, int buf) {
#pragma unroll
    for (int i = 0; i < 4; ++i) {
      int c = w * 256 + i * 64 + l;
      int j = c >> 4, cc = (c & 15) ^ (j & 7);
      load_lds16(kbase + ((size_t)(kt * 64 + j) * 128 + cc * 8),
                 (char*)sK + buf * 16384 + (w * 4096 + i * 1024));
    }
#pragma unroll
    for (int i = 0; i < 4; ++i) {
      int c = w * 256 + i * 64 + l;
      int d = c >> 3, cc = (c & 7) ^ (d & 7);
      load_lds16(vtbase + ((size_t)d * S + kt * 64 + cc * 8),
                 (char*)sVt + buf * 16384 + (w * 4096 + i * 1024));
    }
  };

  stage(0, 0);
  __syncthreads();

  int cur = 0;
  for (int kt = 0; kt < nt; ++kt) {
    if (kt + 1 < nt) stage(kt + 1, cur ^ 1);   // prefetch overlaps compute

    if (kt * 64 <= qw + 31) {
      const u16* sKc = &sK[cur * 8192];
      const u16* sVc = &sVt[cur * 8192];

      // ---- QK^T swapped: sc = mfma32(K, Q), 16 MFMA ----
      f32x16 sc0, sc1;
#pragma unroll
      for (int r = 0; r < 16; ++r) { sc0[r] = 0.f; sc1[r] = 0.f; }
#pragma unroll
      for (int ks = 0; ks < 8; ++ks) {
        int chk = (2 * ks + hi) ^ (l31 & 7);        // same XOR for j and j+32
        s16x8 kf0 = *(const s16x8*)&sKc[l31 * 128 + chk * 8];
        s16x8 kf1 = *(const s16x8*)&sKc[(32 + l31) * 128 + chk * 8];
        sc0 = __builtin_amdgcn_mfma_f32_32x32x16_bf16(kf0, qb[ks], sc0, 0, 0, 0);
        sc1 = __builtin_amdgcn_mfma_f32_32x32x16_bf16(kf1, qb[ks], sc1, 0, 0, 0);
      }

      // ---- causal mask (diagonal tiles only) ----
      if (kt * 64 + 63 > qw) {
        const int j0 = kt * 64;
#pragma unroll
        for (int r = 0; r < 16; ++r) {
          int jr = j0 + (r & 3) + 8 * (r >> 2) + 4 * hi;
          sc0[r] = (jr <= q_glob) ? sc0[r] : -3e38f;
          sc1[r] = (jr + 32 <= q_glob) ? sc1[r] : -3e38f;
        }
      }

      // ---- online softmax (per-lane q, exp2 domain, defer-max THR=8) ----
      float mt = -3e38f;
#pragma unroll
      for (int r = 0; r < 16; ++r) mt = fmaxf(mt, fmaxf(sc0[r], sc1[r]));
      mt = fmaxf(mt, __shfl_xor(mt, 32));
      float mt2 = mt * C2;
      bool resc = (mt2 > mrun + 8.0f);
      if (resc) {
        float Mn = mt2;
        float corr = exp2f(mrun - Mn);
        lsum *= corr;
#pragma unroll
        for (int r = 0; r < 16; ++r) {
          o0[r] *= corr; o1[r] *= corr; o2[r] *= corr; o3[r] *= corr;
        }
        mrun = Mn;
      }
      const float Mn = mrun;

      // p = exp2(sc*C2 - Mn), packed to bf16 pairs
      unsigned pk[16];
      float lacc = 0.0f;
#pragma unroll
      for (int m = 0; m < 8; ++m) {
        float pa_ = exp2f(__builtin_fmaf(sc0[2 * m], C2, -Mn));
        float pb_ = exp2f(__builtin_fmaf(sc0[2 * m + 1], C2, -Mn));
        lacc += pa_ + pb_;
        pk[m] = (bfbits_t(pb_) << 16) | bfbits_t(pa_);
      }
#pragma unroll
      for (int m = 0; m < 8; ++m) {
        float pa_ = exp2f(__builtin_fmaf(sc1[2 * m], C2, -Mn));
        float pb_ = exp2f(__builtin_fmaf(sc1[2 * m + 1], C2, -Mn));
        lacc += pa_ + pb_;
        pk[8 + m] = (bfbits_t(pb_) << 16) | bfbits_t(pa_);
      }
      lsum += lacc;

      // exchange j-halves with partner lane (l ^ 32)
      unsigned pkx[16];
#pragma unroll
      for (int i = 0; i < 16; ++i) pkx[i] = __shfl_xor(pk[i], 32);

      // ---- PV: o[dt] += Vt-frag x P-frag, 16 MFMA ----
#pragma unroll
      for (int ks = 0; ks < 4; ++ks) {
        const int base = (ks >> 1) * 8 + 4 * (ks & 1);
        unsigned pw[4];
        pw[0] = hi ? pkx[base + 2] : pk[base + 0];
        pw[1] = hi ? pkx[base + 3] : pk[base + 1];
        pw[2] = hi ? pk[base + 2] : pkx[base + 0];
        pw[3] = hi ? pk[base + 3] : pkx[base + 1];
        s16x8 pa = *(const s16x8*)pw;
#pragma unroll
        for (int dt = 0; dt < 4; ++dt) {
          int d = dt * 32 + l31;
          s16x8 vt = *(const s16x8*)&sVc[d * 64 + (((2 * ks + hi) ^ (d & 7)) * 8)];
          if (dt == 0) o0 = __builtin_amdgcn_mfma_f32_32x32x16_bf16(vt, pa, o0, 0, 0, 0);
          if (dt == 1) o1 = __builtin_amdgcn_mfma_f32_32x32x16_bf16(vt, pa, o1, 0, 0, 0);
          if (dt == 2) o2 = __builtin_amdgcn_mfma_f32_32x32x16_bf16(vt, pa, o2, 0, 0, 0);
          if (dt == 3) o3 = __builtin_amdgcn_mfma_f32_32x32x16_bf16(vt, pa, o3, 0, 0, 0);
        }
      }
    }

    __syncthreads();   // drains vmcnt (next buf staged) + protects cur buf reuse
    cur ^= 1;
  }

  // ---- epilogue: denominator (2-lane reduce), normalize, packed stores ----
  float ls = lsum + __shfl_xor(lsum, 32);
  float inv = 1.0f / ls;
  size_t obase = ((size_t)b * S + q_glob) * 2048 + h * 128;
#pragma unroll
  for (int dt = 0; dt < 4; ++dt) {
    const f32x16& ov = (dt == 0) ? o0 : (dt == 1) ? o1 : (dt == 2) ? o2 : o3;
#pragma unroll
    for (int g = 0; g < 4; ++g) {
      int d0 = dt * 32 + 8 * g + 4 * hi;
      unsigned u0 = (unsigned)f2bf(ov[4 * g] * inv) | ((unsigned)f2bf(ov[4 * g + 1] * inv) << 16);
      unsigned u1 = (unsigned)f2bf(ov[4 * g + 2] * inv) | ((unsigned)f2bf(ov[4 * g + 3] * inv) << 16);
      uint2 u; u.x = u0; u.y = u1;
      *(uint2*)&O[obase + d0] = u;
    }
  }
}

// ---------------- launch ----------------

extern "C" void kernel_launch(void* const* d_in, const int* in_sizes, int n_in,
                              void* d_out, int out_size, void* d_ws, size_t ws_size,
                              hipStream_t stream) {
  const float* x  = (const float*)d_in[0];
  const float* wq = (const float*)d_in[1];
  const float* bq = (const float*)d_in[2];
  const float* wk = (const float*)d_in[3];
  const float* bk = (const float*)d_in[4];
  const float* wv = (const float*)d_in[5];
  const float* bv = (const float*)d_in[6];
  const float* wo = (const float*)d_in[7];
  float* out = (float*)d_out;

  char* ws = (char*)d_ws;
  u16* xb    = (u16*)ws;    ws += (size_t)4096 * 2048 * 2;
  u16* wqkv  = (u16*)ws;    ws += (size_t)3072 * 2048 * 2;
  float* bqkv = (float*)ws; ws += (size_t)3072 * 4;
  u16* wob   = (u16*)ws;    ws += (size_t)2048 * 2048 * 2;
  u16* Qb    = (u16*)ws;    ws += (size_t)32 * 2048 * 128 * 2;
  u16* Kbuf  = (u16*)ws;    ws += (size_t)8 * 2048 * 128 * 2;
  u16* Vbuf  = (u16*)ws;    ws += (size_t)8 * 2048 * 128 * 2;
  u16* Vt    = (u16*)ws;    ws += (size_t)8 * 128 * 2048 * 2;
  float* cosb = (float*)ws; ws += (size_t)2048 * 64 * 4;
  float* sinb = (float*)ws; ws += (size_t)2048 * 64 * 4;
  u16* att   = (u16*)ws;    ws += (size_t)4096 * 2048 * 2;

  cast_bf16_kernel<<<8192, 256, 0, stream>>>(x, xb, 4096 * 2048 / 4);
  pack_qkv_w_kernel<<<6144, 256, 0, stream>>>(wq, wk, wv, wqkv);
  pack_bias_kernel<<<12, 256, 0, stream>>>(bq, bk, bv, bqkv);
  cast_bf16_kernel<<<4096, 256, 0, stream>>>(wo, wob, 2048 * 2048 / 4);
  rope_table_kernel<<<512, 256, 0, stream>>>(cosb, sinb);

  gemm_bt_kernel<<<dim3(24, 32), 256, 0, stream>>>(xb, wqkv, bqkv, nullptr, 0,
                                                   Qb, Kbuf, Vbuf, 4096, 3072, 2048, 0);
  transpose_v_kernel<<<dim3(8, 32), 256, 0, stream>>>(Vbuf, Vt);
  rope_kernel<<<16384, 256, 0, stream>>>(Qb, cosb, sinb, 32 * 2048 * 64);
  rope_kernel<<<4096, 256, 0, stream>>>(Kbuf, cosb, sinb, 8 * 2048 * 64);

  flash_mfma_kernel<<<dim3(32, 16), 256, 0, stream>>>(Qb, Kbuf, Vt, att);

  gemm_bt_kernel<<<dim3(16, 32), 256, 0, stream>>>(att, wob, nullptr, out, 2048,
                                                   nullptr, nullptr, nullptr, 4096, 2048, 2048, 1);
}